// Round 1
// baseline (189.944 us; speedup 1.0000x reference)
//
#include <hip/hip_runtime.h>
#include <math.h>

#define FDIM 2048
#define GDIM 2048
#define NSIM 16
#define BATCH 32

// Workspace layout (floats):
//   [0,      65536) Lsum  : B*G partial exp-sums (atomic-accumulated, must be zeroed)
//   [65536,  73728) M     : B*16*16 gram of T (atomic-accumulated, must be zeroed)
//   [73728,  74240) cvec  : B*16
//   [74240,  82432) V     : B*16*16  V[b][s][j] = sum_t M[s,t]W[j,t] + W[j,16+s]
//   [82432,  82944) w0eff : B*16     bias[j] - sum_t c[t]W[j,t]

// ---------------------------------------------------------------------------
// Kernel A: the hot loop. For each (b,g): Lsum[b,g] += sum over this block's
// f-range of exp( dot16(A[:,f], T[:,g]) ).
// grid (2, 8, 32), block 256. Each thread owns 4 consecutive g columns.
// A f-tile (256x16) staged in LDS, read as wave-uniform float4 broadcasts.
// ---------------------------------------------------------------------------
__global__ __launch_bounds__(256) void kA_lse(const float* __restrict__ data,
                                              const float* __restrict__ attn,
                                              float* __restrict__ Lsum) {
    __shared__ float Al[256 * 16];  // [fi][s], 16 KB
    const int tid = threadIdx.x;
    const int b  = blockIdx.z;
    const int f0 = blockIdx.y * 256;
    const int g0 = (blockIdx.x * 256 + tid) * 4;

    // Stage A tile: Al[fi][s] = data[(b*16+s)*FDIM + f0+fi]   (coalesced reads)
    const float* Abase = data + (size_t)b * NSIM * FDIM + f0;
#pragma unroll
    for (int s = 0; s < NSIM; ++s) {
        Al[tid * 16 + s] = Abase[(size_t)s * FDIM + tid];
    }

    // T columns for this thread's 4 g's: tg[s] = attn[(b*16+s)*GDIM + g0..g0+3]
    const float* Tbase = attn + (size_t)b * NSIM * GDIM + g0;
    float4 tg[NSIM];
#pragma unroll
    for (int s = 0; s < NSIM; ++s) {
        tg[s] = *(const float4*)(Tbase + (size_t)s * GDIM);
    }
    __syncthreads();

    float sum0 = 0.f, sum1 = 0.f, sum2 = 0.f, sum3 = 0.f;
    for (int fi = 0; fi < 256; ++fi) {
        const float4* ap = (const float4*)(Al + fi * 16);
        float av[16];
        *(float4*)(av + 0)  = ap[0];
        *(float4*)(av + 4)  = ap[1];
        *(float4*)(av + 8)  = ap[2];
        *(float4*)(av + 12) = ap[3];
        float d0 = 0.f, d1 = 0.f, d2 = 0.f, d3 = 0.f;
#pragma unroll
        for (int s = 0; s < NSIM; ++s) {
            d0 += av[s] * tg[s].x;
            d1 += av[s] * tg[s].y;
            d2 += av[s] * tg[s].z;
            d3 += av[s] * tg[s].w;
        }
        // |d| << 88 -> no max-subtraction needed in fp32
        sum0 += __expf(d0);
        sum1 += __expf(d1);
        sum2 += __expf(d2);
        sum3 += __expf(d3);
    }
    float* Lp = Lsum + (size_t)b * GDIM + g0;
    atomicAdd(Lp + 0, sum0);
    atomicAdd(Lp + 1, sum1);
    atomicAdd(Lp + 2, sum2);
    atomicAdd(Lp + 3, sum3);
}

// ---------------------------------------------------------------------------
// Kernel M: partial gram M[b][s][t] += sum over 128-g chunk of T[s,g]T[t,g].
// grid (16, 32), block 256 (one thread per (s,t) pair).
// ---------------------------------------------------------------------------
__global__ __launch_bounds__(256) void kM(const float* __restrict__ attn,
                                          float* __restrict__ M) {
    __shared__ float Tl[NSIM * 132];  // [s][132] padded
    const int tid = threadIdx.x;
    const int b  = blockIdx.y;
    const int g0 = blockIdx.x * 128;
    const float* Tbase = attn + (size_t)b * NSIM * GDIM;
#pragma unroll
    for (int k = 0; k < 8; ++k) {
        int e = k * 256 + tid;
        int s = e >> 7, g = e & 127;
        Tl[s * 132 + g] = Tbase[(size_t)s * GDIM + g0 + g];
    }
    __syncthreads();
    const int s = tid >> 4, t = tid & 15;
    const float* ps = Tl + s * 132;
    const float* pt = Tl + t * 132;
    float acc = 0.f;
#pragma unroll 8
    for (int g = 0; g < 128; ++g) acc += ps[g] * pt[g];
    atomicAdd(&M[(size_t)b * 256 + tid], acc);
}

// ---------------------------------------------------------------------------
// Kernel B: L[g] = log(Lsum[g]);  c[t] = sum_g L[g]*T[t,g].
// grid (32), block 256.
// ---------------------------------------------------------------------------
__global__ __launch_bounds__(256) void kB(const float* __restrict__ attn,
                                          const float* __restrict__ Lsum,
                                          float* __restrict__ cvec) {
    __shared__ float Ll[GDIM];       // 8 KB
    __shared__ float red[16][17];
    const int tid = threadIdx.x;
    const int b = blockIdx.x;
#pragma unroll
    for (int k = 0; k < 8; ++k) {
        int g = k * 256 + tid;
        Ll[g] = __logf(Lsum[(size_t)b * GDIM + g]);
    }
    __syncthreads();
    const int t = tid & 15, i = tid >> 4;  // t: output idx, i: g-phase
    const float* Trow = attn + (size_t)(b * NSIM + t) * GDIM;
    float acc = 0.f;
#pragma unroll 4
    for (int k = 0; k < 128; ++k) {
        int g = i + 16 * k;
        acc += Ll[g] * Trow[g];
    }
    red[t][i] = acc;
    __syncthreads();
    if (tid < 16) {
        float s = 0.f;
#pragma unroll
        for (int k = 0; k < 16; ++k) s += red[tid][k];
        cvec[b * 16 + tid] = s;
    }
}

// ---------------------------------------------------------------------------
// Kernel B2: fold M,c,W,bias into V[b][s][j] and w0eff[b][j].
// grid (32), block 256 (thread = s*16+j).
// ---------------------------------------------------------------------------
__global__ __launch_bounds__(256) void kB2(const float* __restrict__ M,
                                           const float* __restrict__ cvec,
                                           const float* __restrict__ W,
                                           const float* __restrict__ bias,
                                           float* __restrict__ V,
                                           float* __restrict__ w0eff) {
    const int b = blockIdx.x;
    const int tid = threadIdx.x;
    const int s = tid >> 4, j = tid & 15;
    float acc = 0.f;
#pragma unroll
    for (int t = 0; t < 16; ++t) acc += M[(size_t)b * 256 + s * 16 + t] * W[j * 32 + t];
    V[(size_t)b * 256 + s * 16 + j] = acc + W[j * 32 + 16 + s];
    if (s == 0) {
        float w0 = 0.f;
#pragma unroll
        for (int t = 0; t < 16; ++t) w0 += cvec[b * 16 + t] * W[j * 32 + t];
        w0eff[b * 16 + j] = bias[j] - w0;
    }
}

// ---------------------------------------------------------------------------
// Kernel C: epilogue. pre[j] = w0eff[j] + sum_s A[s,f]*V[s][j];
// out[(j*32+b)*F+f] = sigmoid(pre)*data[(j*32+b)*F+f].
// grid (8, 32), block 256.
// ---------------------------------------------------------------------------
__global__ __launch_bounds__(256) void kC(const float* __restrict__ data,
                                          const float* __restrict__ V,
                                          const float* __restrict__ w0eff,
                                          float* __restrict__ out) {
    const int tid = threadIdx.x;
    const int b = blockIdx.y;
    const int f = blockIdx.x * 256 + tid;
    float As[NSIM];
#pragma unroll
    for (int s = 0; s < NSIM; ++s)
        As[s] = data[(size_t)(b * NSIM + s) * FDIM + f];
    const float* Vb = V + (size_t)b * 256;
    const float* w0 = w0eff + b * 16;
#pragma unroll
    for (int j = 0; j < NSIM; ++j) {
        float p = w0[j];
#pragma unroll
        for (int s = 0; s < NSIM; ++s) p += As[s] * Vb[s * 16 + j];
        float gate = 1.0f / (1.0f + __expf(-p));
        size_t r = (size_t)(j * 32 + b) * FDIM + f;
        out[r] = gate * data[r];
    }
}

extern "C" void kernel_launch(void* const* d_in, const int* in_sizes, int n_in,
                              void* d_out, int out_size, void* d_ws, size_t ws_size,
                              hipStream_t stream) {
    const float* data = (const float*)d_in[0];
    const float* attn = (const float*)d_in[1];
    const float* W    = (const float*)d_in[2];
    const float* bias = (const float*)d_in[3];
    float* out = (float*)d_out;

    float* ws    = (float*)d_ws;
    float* Lsum  = ws;            // 65536
    float* M     = ws + 65536;    // 8192
    float* cvec  = ws + 73728;    // 512
    float* V     = ws + 74240;    // 8192
    float* w0eff = ws + 82432;    // 512

    // Zero the atomic accumulators (Lsum + M are contiguous).
    hipMemsetAsync(d_ws, 0, (65536 + 8192) * sizeof(float), stream);

    kA_lse<<<dim3(2, 8, BATCH), 256, 0, stream>>>(data, attn, Lsum);
    kM<<<dim3(16, BATCH), 256, 0, stream>>>(attn, M);
    kB<<<dim3(BATCH), 256, 0, stream>>>(attn, Lsum, cvec);
    kB2<<<dim3(BATCH), 256, 0, stream>>>(M, cvec, W, bias, V, w0eff);
    kC<<<dim3(8, BATCH), 256, 0, stream>>>(data, V, w0eff, out);
}